// Round 1
// baseline (1115.394 us; speedup 1.0000x reference)
//
#include <hip/hip_runtime.h>
#include <hip/hip_bf16.h>

// WordSentAtt: qf = relu(Q@W^T + b); S = qf@K^T (masked); attn = softmax; O = attn@K
// B=32, Lq=Lk=D=1024. All f32 in/out. Split-bf16 (hi/lo) MFMA for qf and S
// (softmax is near-argmax; plain bf16 logit error would exceed threshold).
// d_out is used as scratch: K1 writes qf f32; K2 overwrites bytes [2048,4096)
// of its own rows with attn bf16; K3 (two launches, d-halves) writes final O.
// No d_ws usage.

typedef __attribute__((ext_vector_type(4))) float f32x4;
typedef __attribute__((ext_vector_type(8))) short s16x8;

#define MFMA16(a, b, c) __builtin_amdgcn_mfma_f32_16x16x32_bf16((a), (b), (c), 0, 0, 0)

__device__ __forceinline__ unsigned short f2bf(float x) {
  unsigned u = __builtin_bit_cast(unsigned, x);
  return (unsigned short)((u + 0x7FFFu + ((u >> 16) & 1u)) >> 16);
}
__device__ __forceinline__ float bf2f(unsigned short h) {
  return __builtin_bit_cast(float, ((unsigned)h) << 16);
}
// XOR swizzle for [R][64]-short LDS tiles read via b128 (rows stride 128B).
__device__ __forceinline__ int swz(int row, int col) {
  return (row * 64 + col) ^ ((row & 7) << 3);
}
// Load 8 f32, produce hi/lo bf16 split.
__device__ __forceinline__ void cvt8(const float* __restrict__ s, s16x8& h8, s16x8& l8) {
  f32x4 a = *(const f32x4*)s;
  f32x4 b = *(const f32x4*)(s + 4);
#pragma unroll
  for (int i = 0; i < 8; i++) {
    float v = (i < 4) ? a[i] : b[i - 4];
    unsigned short hu = f2bf(v);
    unsigned short lu = f2bf(v - bf2f(hu));
    h8[i] = (short)hu;
    l8[i] = (short)lu;
  }
}

// ---------------- K1: qf = relu(Q @ W^T + b), f32 out into d_out ----------------
// grid (256, 8): 128x128 tile, 256 thr = 4 waves (2x2), split-bf16 3-product GEMM.
__global__ __launch_bounds__(256, 2) void k_qf(const float* __restrict__ Q,
                                               const float* __restrict__ W,
                                               const float* __restrict__ bias,
                                               float* __restrict__ qf) {
  __shared__ __align__(16) short Ah[128 * 64], Al[128 * 64], Bh[128 * 64], Bl[128 * 64];
  const int t = threadIdx.x;
  const int m0 = blockIdx.x * 128, n0 = blockIdx.y * 128;
  const int w = t >> 6, l = t & 63, wm = w >> 1, wn = w & 1, g = l >> 4, ln = l & 15;
  const f32x4 fz = {0.f, 0.f, 0.f, 0.f};
  f32x4 acc[4][4];
#pragma unroll
  for (int i = 0; i < 4; i++)
#pragma unroll
    for (int j = 0; j < 4; j++) acc[i][j] = fz;
  const int srow = t >> 1, scol = (t & 1) * 32;
#pragma unroll 1
  for (int k0 = 0; k0 < 1024; k0 += 64) {
    const float* sa = Q + (size_t)(m0 + srow) * 1024 + k0 + scol;
    const float* sb = W + (size_t)(n0 + srow) * 1024 + k0 + scol;
#pragma unroll
    for (int c = 0; c < 32; c += 8) {
      s16x8 h, lo;
      cvt8(sa + c, h, lo);
      int si = swz(srow, scol + c);
      *(s16x8*)&Ah[si] = h;
      *(s16x8*)&Al[si] = lo;
    }
#pragma unroll
    for (int c = 0; c < 32; c += 8) {
      s16x8 h, lo;
      cvt8(sb + c, h, lo);
      int si = swz(srow, scol + c);
      *(s16x8*)&Bh[si] = h;
      *(s16x8*)&Bl[si] = lo;
    }
    __syncthreads();
#pragma unroll
    for (int ks = 0; ks < 2; ks++) {
      const int kc = ks * 32 + g * 8;
      s16x8 ah[4], al[4], bh[4], bl[4];
#pragma unroll
      for (int mf = 0; mf < 4; mf++) {
        int si = swz(wm * 64 + mf * 16 + ln, kc);
        ah[mf] = *(s16x8*)&Ah[si];
        al[mf] = *(s16x8*)&Al[si];
      }
#pragma unroll
      for (int nf = 0; nf < 4; nf++) {
        int si = swz(wn * 64 + nf * 16 + ln, kc);
        bh[nf] = *(s16x8*)&Bh[si];
        bl[nf] = *(s16x8*)&Bl[si];
      }
#pragma unroll
      for (int mf = 0; mf < 4; mf++)
#pragma unroll
        for (int nf = 0; nf < 4; nf++) {
          acc[mf][nf] = MFMA16(ah[mf], bh[nf], acc[mf][nf]);
          acc[mf][nf] = MFMA16(ah[mf], bl[nf], acc[mf][nf]);
          acc[mf][nf] = MFMA16(al[mf], bh[nf], acc[mf][nf]);
        }
    }
    __syncthreads();
  }
#pragma unroll
  for (int nf = 0; nf < 4; nf++) {
    const int col = n0 + wn * 64 + nf * 16 + ln;
    const float bv = bias[col];
#pragma unroll
    for (int mf = 0; mf < 4; mf++)
#pragma unroll
      for (int r = 0; r < 4; r++) {
        const int row = m0 + wm * 64 + mf * 16 + g * 4 + r;
        float v = acc[mf][nf][r] + bv;
        qf[(size_t)row * 1024 + col] = v > 0.f ? v : 0.f;
      }
  }
}

// ---------------- K2: S = qf @ K^T, masked softmax, attn(bf16) -> d_out rows +2048 ----
// grid (16, 32): block = (qtile of 64 rows, batch b), 512 thr = 8 waves (2 wm x 4 wn).
// S[64][1024] lives in regs: acc[8 ktiles][2 mf][2 nf] = 128 VGPR/thread.
__global__ __launch_bounds__(512, 2) void k_attn(const float* __restrict__ Key,
                                                 const float* __restrict__ mask,
                                                 float* __restrict__ dout) {
  __shared__ __align__(16) short qh[64 * 64], qlo[64 * 64], kh[128 * 64], klo[128 * 64];
  __shared__ float mask_s[1024];
  __shared__ float red[4][64];
  const int t = threadIdx.x;
  const int qt = blockIdx.x, b = blockIdx.y;
  const int q0 = qt * 64;
  const int w = t >> 6, l = t & 63, wm = w >> 2, wn = w & 3, g = l >> 4, ln = l & 15;
  for (int i = t; i < 1024; i += 512) mask_s[i] = mask[b * 1024 + i];
  const f32x4 fz = {0.f, 0.f, 0.f, 0.f};
  f32x4 acc[8][2][2];
#pragma unroll
  for (int kt = 0; kt < 8; kt++)
#pragma unroll
    for (int mf = 0; mf < 2; mf++)
#pragma unroll
      for (int nf = 0; nf < 2; nf++) acc[kt][mf][nf] = fz;
  const float* qfb = dout + (size_t)(b * 1024 + q0) * 1024;
  const float* kb = Key + (size_t)b * 1024 * 1024;
  const int qrow = t >> 3, qcol = (t & 7) * 8;
  const int krow = t >> 2, kcol0 = (t & 3) * 16;
#pragma unroll 1
  for (int dc = 0; dc < 16; dc++) {
    {  // stage qf tile (64x64) hi/lo -- protected by previous iteration's trailing sync
      s16x8 h, lo;
      cvt8(qfb + (size_t)qrow * 1024 + dc * 64 + qcol, h, lo);
      int si = swz(qrow, qcol);
      *(s16x8*)&qh[si] = h;
      *(s16x8*)&qlo[si] = lo;
    }
#pragma unroll
    for (int kt = 0; kt < 8; kt++) {
      {  // stage key tile (128x64) hi/lo
        const float* s = kb + (size_t)(kt * 128 + krow) * 1024 + dc * 64 + kcol0;
        s16x8 h, lo;
        cvt8(s, h, lo);
        int si = swz(krow, kcol0);
        *(s16x8*)&kh[si] = h;
        *(s16x8*)&klo[si] = lo;
        cvt8(s + 8, h, lo);
        si = swz(krow, kcol0 + 8);
        *(s16x8*)&kh[si] = h;
        *(s16x8*)&klo[si] = lo;
      }
      __syncthreads();
#pragma unroll
      for (int ks = 0; ks < 2; ks++) {
        const int kc = ks * 32 + g * 8;
        s16x8 ah[2], al2[2], bh[2], bl[2];
#pragma unroll
        for (int mf = 0; mf < 2; mf++) {
          int si = swz(wm * 32 + mf * 16 + ln, kc);
          ah[mf] = *(s16x8*)&qh[si];
          al2[mf] = *(s16x8*)&qlo[si];
        }
#pragma unroll
        for (int nf = 0; nf < 2; nf++) {
          int si = swz(wn * 32 + nf * 16 + ln, kc);
          bh[nf] = *(s16x8*)&kh[si];
          bl[nf] = *(s16x8*)&klo[si];
        }
#pragma unroll
        for (int mf = 0; mf < 2; mf++)
#pragma unroll
          for (int nf = 0; nf < 2; nf++) {
            acc[kt][mf][nf] = MFMA16(ah[mf], bh[nf], acc[kt][mf][nf]);
            acc[kt][mf][nf] = MFMA16(ah[mf], bl[nf], acc[kt][mf][nf]);
            acc[kt][mf][nf] = MFMA16(al2[mf], bh[nf], acc[kt][mf][nf]);
          }
      }
      __syncthreads();
    }
  }
  // ---- masked softmax over k (rows = q). C/D layout: col(k)=ln, row=(g)*4+r.
  float rmax[2][4];
#pragma unroll
  for (int mf = 0; mf < 2; mf++)
#pragma unroll
    for (int r = 0; r < 4; r++) rmax[mf][r] = -1e30f;
#pragma unroll
  for (int kt = 0; kt < 8; kt++)
#pragma unroll
    for (int nf = 0; nf < 2; nf++) {
      const int k = kt * 128 + wn * 32 + nf * 16 + ln;
      const bool mk = mask_s[k] != 0.f;
#pragma unroll
      for (int mf = 0; mf < 2; mf++)
#pragma unroll
        for (int r = 0; r < 4; r++)
          if (mk) rmax[mf][r] = fmaxf(rmax[mf][r], acc[kt][mf][nf][r]);
    }
#pragma unroll
  for (int off = 1; off < 16; off <<= 1)
#pragma unroll
    for (int mf = 0; mf < 2; mf++)
#pragma unroll
      for (int r = 0; r < 4; r++) rmax[mf][r] = fmaxf(rmax[mf][r], __shfl_xor(rmax[mf][r], off));
  if (ln == 0) {
#pragma unroll
    for (int mf = 0; mf < 2; mf++)
#pragma unroll
      for (int r = 0; r < 4; r++) red[wn][wm * 32 + mf * 16 + g * 4 + r] = rmax[mf][r];
  }
  __syncthreads();
#pragma unroll
  for (int mf = 0; mf < 2; mf++)
#pragma unroll
    for (int r = 0; r < 4; r++) {
      const int row = wm * 32 + mf * 16 + g * 4 + r;
      rmax[mf][r] = fmaxf(fmaxf(red[0][row], red[1][row]), fmaxf(red[2][row], red[3][row]));
    }
  __syncthreads();
  float rsum[2][4];
#pragma unroll
  for (int mf = 0; mf < 2; mf++)
#pragma unroll
    for (int r = 0; r < 4; r++) rsum[mf][r] = 0.f;
#pragma unroll
  for (int kt = 0; kt < 8; kt++)
#pragma unroll
    for (int nf = 0; nf < 2; nf++) {
      const int k = kt * 128 + wn * 32 + nf * 16 + ln;
      const bool mk = mask_s[k] != 0.f;
#pragma unroll
      for (int mf = 0; mf < 2; mf++)
#pragma unroll
        for (int r = 0; r < 4; r++)
          if (mk) rsum[mf][r] += __expf(acc[kt][mf][nf][r] - rmax[mf][r]);
    }
#pragma unroll
  for (int off = 1; off < 16; off <<= 1)
#pragma unroll
    for (int mf = 0; mf < 2; mf++)
#pragma unroll
      for (int r = 0; r < 4; r++) rsum[mf][r] += __shfl_xor(rsum[mf][r], off);
  if (ln == 0) {
#pragma unroll
    for (int mf = 0; mf < 2; mf++)
#pragma unroll
      for (int r = 0; r < 4; r++) red[wn][wm * 32 + mf * 16 + g * 4 + r] = rsum[mf][r];
  }
  __syncthreads();
  float rinv[2][4];
#pragma unroll
  for (int mf = 0; mf < 2; mf++)
#pragma unroll
    for (int r = 0; r < 4; r++) {
      const int row = wm * 32 + mf * 16 + g * 4 + r;
      float s4 = red[0][row] + red[1][row] + red[2][row] + red[3][row];
      rinv[mf][r] = 1.f / s4;  // s4 >= 1 whenever any key unmasked
    }
  // ---- write attn bf16 into this block's own rows, bytes [2048, 4096)
  char* oc = (char*)dout;
#pragma unroll
  for (int kt = 0; kt < 8; kt++)
#pragma unroll
    for (int nf = 0; nf < 2; nf++) {
      const int k = kt * 128 + wn * 32 + nf * 16 + ln;
      const bool mk = mask_s[k] != 0.f;
#pragma unroll
      for (int mf = 0; mf < 2; mf++)
#pragma unroll
        for (int r = 0; r < 4; r++) {
          const int q = q0 + wm * 32 + mf * 16 + g * 4 + r;
          float p = mk ? __expf(acc[kt][mf][nf][r] - rmax[mf][r]) * rinv[mf][r] : 0.f;
          *(unsigned short*)(oc + (size_t)(b * 1024 + q) * 4096 + 2048 + k * 2) = f2bf(p);
        }
    }
}

// ---------------- K3: O = attn @ K (plain bf16). Launched twice (dh=0 then dh=1) ------
// grid (8, 32): block = (qtile of 128, b); 512 thr = 8 waves (2 wm x 4 wd), 128q x 512d.
// Key staged transposed into LDS (coalesced global reads along d, b128 writes along k).
__global__ __launch_bounds__(512, 2) void k_pv(const float* __restrict__ Key,
                                               float* __restrict__ dout, const int dh) {
  __shared__ __align__(16) short P[128 * 64];
  __shared__ __align__(16) short KT[512 * 64];
  const int t = threadIdx.x;
  const int qt = blockIdx.x, b = blockIdx.y;
  const int q0 = qt * 128, d0 = dh * 512;
  const int w = t >> 6, l = t & 63, wm = w >> 2, wd = w & 3, g = l >> 4, ln = l & 15;
  const f32x4 fz = {0.f, 0.f, 0.f, 0.f};
  f32x4 acc[4][8];
#pragma unroll
  for (int i = 0; i < 4; i++)
#pragma unroll
    for (int j = 0; j < 8; j++) acc[i][j] = fz;
  const char* ab = (const char*)dout;
  const int prow = t >> 2, pc0 = (t & 3) * 16;
#pragma unroll 1
  for (int k0 = 0; k0 < 1024; k0 += 64) {
    {  // stage P (attn) 128x64 bf16
      const unsigned short* s =
          (const unsigned short*)(ab + (size_t)(b * 1024 + q0 + prow) * 4096 + 2048) + k0 + pc0;
      s16x8 p0 = *(const s16x8*)s, p1 = *(const s16x8*)(s + 8);
      *(s16x8*)&P[swz(prow, pc0)] = p0;
      *(s16x8*)&P[swz(prow, pc0 + 8)] = p1;
    }
    {  // stage K transposed: KT[d][k], thread t owns d = t
      const float* ksrc = Key + (size_t)b * 1024 * 1024 + (size_t)k0 * 1024 + d0 + t;
#pragma unroll
      for (int kg = 0; kg < 8; kg++) {
        s16x8 h;
#pragma unroll
        for (int j = 0; j < 8; j++) h[j] = (short)f2bf(ksrc[(size_t)(kg * 8 + j) * 1024]);
        *(s16x8*)&KT[swz(t, kg * 8)] = h;
      }
    }
    __syncthreads();
#pragma unroll
    for (int ks = 0; ks < 2; ks++) {
      const int kc = ks * 32 + g * 8;
      s16x8 a[4], bb[8];
#pragma unroll
      for (int mf = 0; mf < 4; mf++) a[mf] = *(s16x8*)&P[swz(wm * 64 + mf * 16 + ln, kc)];
#pragma unroll
      for (int nf = 0; nf < 8; nf++) bb[nf] = *(s16x8*)&KT[swz(wd * 128 + nf * 16 + ln, kc)];
#pragma unroll
      for (int mf = 0; mf < 4; mf++)
#pragma unroll
        for (int nf = 0; nf < 8; nf++) acc[mf][nf] = MFMA16(a[mf], bb[nf], acc[mf][nf]);
    }
    __syncthreads();
  }
#pragma unroll
  for (int mf = 0; mf < 4; mf++)
#pragma unroll
    for (int nf = 0; nf < 8; nf++)
#pragma unroll
      for (int r = 0; r < 4; r++) {
        const int q = q0 + wm * 64 + mf * 16 + g * 4 + r;
        const int d = d0 + wd * 128 + nf * 16 + ln;
        dout[(size_t)(b * 1024 + q) * 1024 + d] = acc[mf][nf][r];
      }
}

extern "C" void kernel_launch(void* const* d_in, const int* in_sizes, int n_in,
                              void* d_out, int out_size, void* d_ws, size_t ws_size,
                              hipStream_t stream) {
  const float* Q = (const float*)d_in[0];
  const float* K = (const float*)d_in[1];
  const float* M = (const float*)d_in[2];
  const float* W = (const float*)d_in[3];
  const float* bias = (const float*)d_in[4];
  float* out = (float*)d_out;
  (void)d_ws; (void)ws_size; (void)in_sizes; (void)n_in; (void)out_size;

  dim3 g1(256, 8);
  k_qf<<<g1, 256, 0, stream>>>(Q, W, bias, out);
  dim3 g2(16, 32);
  k_attn<<<g2, 512, 0, stream>>>(K, M, out);
  dim3 g3(8, 32);
  // dh=0 must fully complete before dh=1 (dh=1's epilogue overwrites the attn
  // bytes that dh=0 reads) -- guaranteed by stream ordering of the two launches.
  k_pv<<<g3, 512, 0, stream>>>(K, out, 0);
  k_pv<<<g3, 512, 0, stream>>>(K, out, 1);
}